// Round 4
// baseline (178.014 us; speedup 1.0000x reference)
//
#include <hip/hip_runtime.h>
#include <math.h>

#define B 8
#define S 128
#define D 256
#define H 8
#define T 129
#define HD 32
#define NEG_INF -1000000000.0f
#define LN_EPS 1e-5f

// ---------------------------------------------------------------------------
// Kernel 1 (single launch for ALL pre-attention work), slabs by blockIdx.x:
//   [0,65)    : v   = nv   @ Wv  + bv          (1032 rows)
//   [65,129)  : U   = desc @ We1[0:256] + be1  (1024 rows)
//   [129,193) : V   = desc @ We1[256:512]      (1024 rows)
//   [193,258) : qdkd = nv @ fold(Wq,Wk,wa) + fold(bq,bk)   (1032 x 16)
//   258       : W2aT[h*D+c] = We2[c, h*32+:].wa_e ; econst[h] = be2[h*32+:].wa_e
// GEMM slabs: 16 rows x 256 cols per block; thread owns cols (c, c+128) for
// 8 rows; W prefetched one 8-k chunk ahead (16 loads in flight).
// ---------------------------------------------------------------------------
__global__ __launch_bounds__(256) void gemm_all(
    const float* __restrict__ nv, const float* __restrict__ desc,
    const float* __restrict__ Wq, const float* __restrict__ bq,
    const float* __restrict__ Wk, const float* __restrict__ bk,
    const float* __restrict__ Wv, const float* __restrict__ bv,
    const float* __restrict__ We1, const float* __restrict__ be1,
    const float* __restrict__ We2, const float* __restrict__ be2,
    const float* __restrict__ wa,
    float* __restrict__ v, float* __restrict__ U, float* __restrict__ V,
    float* __restrict__ qdkd, float* __restrict__ W2aT, float* __restrict__ econst)
{
    const int blk = blockIdx.x;
    const int tid = threadIdx.x;

    __shared__ float xs[16][260];      // row tile (padded: 4-row b128 reads bank-split)
    __shared__ float wq_s[256 * 16];   // qdkd slab: folded Wqk
    __shared__ float bq_s[16];

    if (blk < 193) {
        // ---------------- dense 256-col GEMM slabs ----------------
        const float* X; const float* W; const float* bias; float* out; int rows; int r0;
        if (blk < 65)       { X = nv;   W = Wv;        bias = bv;      out = v; rows = B*T; r0 = blk * 16; }
        else if (blk < 129) { X = desc; W = We1;       bias = be1;     out = U; rows = B*S; r0 = (blk - 65) * 16; }
        else                { X = desc; W = We1 + D*D; bias = nullptr; out = V; rows = B*S; r0 = (blk - 129) * 16; }

        for (int t = tid; t < 16 * 256; t += 256) {
            const int r = t >> 8, c = t & 255, rr = r0 + r;
            xs[r][c] = (rr < rows) ? X[rr * D + c] : 0.f;
        }
        __syncthreads();

        const int c  = tid & 127;
        const int rg = (tid >> 7) * 8;   // row offset 0 or 8

        float acc[8][2];
        #pragma unroll
        for (int r = 0; r < 8; ++r) { acc[r][0] = 0.f; acc[r][1] = 0.f; }

        float wA[8], wB[8], nA[8], nB[8];
        #pragma unroll
        for (int q = 0; q < 8; ++q) { wA[q] = W[q*D + c]; wB[q] = W[q*D + c + 128]; }

        for (int kk = 0; kk < 256; kk += 8) {
            const int kn = kk + 8;
            if (kn < 256) {
                #pragma unroll
                for (int q = 0; q < 8; ++q) {
                    nA[q] = W[(kn + q)*D + c];
                    nB[q] = W[(kn + q)*D + c + 128];
                }
            }
            #pragma unroll
            for (int qh = 0; qh < 8; qh += 4) {
                #pragma unroll
                for (int r = 0; r < 8; ++r) {
                    const float4 x = *(const float4*)&xs[rg + r][kk + qh];
                    acc[r][0] = fmaf(x.x, wA[qh+0], acc[r][0]);
                    acc[r][0] = fmaf(x.y, wA[qh+1], acc[r][0]);
                    acc[r][0] = fmaf(x.z, wA[qh+2], acc[r][0]);
                    acc[r][0] = fmaf(x.w, wA[qh+3], acc[r][0]);
                    acc[r][1] = fmaf(x.x, wB[qh+0], acc[r][1]);
                    acc[r][1] = fmaf(x.y, wB[qh+1], acc[r][1]);
                    acc[r][1] = fmaf(x.z, wB[qh+2], acc[r][1]);
                    acc[r][1] = fmaf(x.w, wB[qh+3], acc[r][1]);
                }
            }
            if (kn < 256) {
                #pragma unroll
                for (int q = 0; q < 8; ++q) { wA[q] = nA[q]; wB[q] = nB[q]; }
            }
        }

        const float b0 = bias ? bias[c]       : 0.f;
        const float b1 = bias ? bias[c + 128] : 0.f;
        #pragma unroll
        for (int r = 0; r < 8; ++r) {
            const int rr = r0 + rg + r;
            if (rr < rows) {
                out[rr * D + c]       = acc[r][0] + b0;
                out[rr * D + c + 128] = acc[r][1] + b1;
            }
        }
    } else if (blk < 258) {
        // ---------------- qdkd slab (self-folding) ----------------
        const int r0 = (blk - 193) * 16;

        // fold Wq/Wk -> wq_s[k*16 + cc]  (cc<8: q-heads, cc>=8: k-heads)
        for (int t = tid; t < 4096; t += 256) {
            const int k = t >> 4, cc = t & 15;
            const float* Wsrc = (cc < 8) ? Wq : Wk;
            const float* wap  = (cc < 8) ? wa : wa + HD;
            const int h = cc & 7;
            float s = 0.f;
            #pragma unroll
            for (int d = 0; d < HD; ++d) s = fmaf(Wsrc[k*D + h*HD + d], wap[d], s);
            wq_s[t] = s;
        }
        if (tid < 16) {
            const float* bsrc = (tid < 8) ? bq : bk;
            const float* wap  = (tid < 8) ? wa : wa + HD;
            const int h = tid & 7;
            float s = 0.f;
            #pragma unroll
            for (int d = 0; d < HD; ++d) s = fmaf(bsrc[h*HD + d], wap[d], s);
            bq_s[tid] = s;
        }
        for (int t = tid; t < 16 * 256; t += 256) {
            const int r = t >> 8, c = t & 255, rr = r0 + r;
            xs[r][c] = (rr < B*T) ? nv[rr * D + c] : 0.f;
        }
        __syncthreads();

        const int r = tid >> 4, cc = tid & 15;
        float acc = 0.f;
        for (int kk = 0; kk < 256; kk += 4) {
            const float4 x = *(const float4*)&xs[r][kk];
            acc = fmaf(x.x, wq_s[(kk+0)*16 + cc], acc);
            acc = fmaf(x.y, wq_s[(kk+1)*16 + cc], acc);
            acc = fmaf(x.z, wq_s[(kk+2)*16 + cc], acc);
            acc = fmaf(x.w, wq_s[(kk+3)*16 + cc], acc);
        }
        const int rr = r0 + r;
        if (rr < B*T) qdkd[rr * 16 + cc] = acc + bq_s[cc];
    } else {
        // ---------------- W2a fold + econst ----------------
        for (int t = tid; t < 2048; t += 256) {
            const int h = t >> 8, c = t & 255;
            float s = 0.f;
            #pragma unroll
            for (int d = 0; d < HD; ++d) s = fmaf(We2[c*D + h*HD + d], wa[2*HD + d], s);
            W2aT[h*D + c] = s;
        }
        if (tid < 8) {
            float s = 0.f;
            #pragma unroll
            for (int d = 0; d < HD; ++d) s = fmaf(be2[tid*HD + d], wa[2*HD + d], s);
            econst[tid] = s;
        }
    }
}

// ---------------------------------------------------------------------------
// Kernel 2 (fused): edge LN+relu+head-dot  ->  softmax(+prior)  ->  ctx.
// (unchanged from R3 — passed with absmax 3.9e-3)
// ---------------------------------------------------------------------------
__global__ __launch_bounds__(512) void edge_attn(
    const float* __restrict__ U, const float* __restrict__ V,
    const float* __restrict__ W2aT, const float* __restrict__ econst,
    const float* __restrict__ ln_g, const float* __restrict__ ln_b,
    const float* __restrict__ qdkd, const float* __restrict__ prior,
    const float* __restrict__ v, const float* __restrict__ ba,
    float* __restrict__ out_basis, float* __restrict__ out_attn)
{
    const int bid = blockIdx.x;      // b*T + i
    const int b = bid / T, i = bid % T;
    const int tid = threadIdx.x, lane = tid & 63, wid = tid >> 6;
    const int c0 = lane * 4;

    __shared__ float escl[H][132];
    __shared__ float pat[H][132];

    // ---- Phase A: edge scores ----
    const float4 g4 = *(const float4*)(ln_g + c0);
    const float4 b4 = *(const float4*)(ln_b + c0);
    float4 w[H];
    #pragma unroll
    for (int h = 0; h < H; ++h) w[h] = *(const float4*)(W2aT + h*D + c0);
    float4 u4i = make_float4(0.f, 0.f, 0.f, 0.f);
    if (i >= 1) u4i = *(const float4*)(U + (b*S + (i-1))*D + c0);

    const int hmap = 4*(lane&1) + 2*((lane>>1)&1) + ((lane>>2)&1);
    const float ecl = (lane < 8) ? econst[hmap] : 0.f;

    const int j0 = 1 + wid * 16;
    for (int jj = 0; jj < 16; ++jj) {
        const int j = j0 + jj;                 // 1..128
        if (i >= 1 && j == i) continue;        // wave-uniform skip (never read)

        const float4 v4 = *(const float4*)(V + (b*S + (j-1))*D + c0);
        float4 u4;
        if (i == 0) u4 = *(const float4*)(U + (b*S + (j-1))*D + c0);
        else        u4 = u4i;

        const float y0 = u4.x + v4.x, y1 = u4.y + v4.y;
        const float y2 = u4.z + v4.z, y3 = u4.w + v4.w;

        float s1 = y0 + y1 + y2 + y3;
        float s2 = fmaf(y0, y0, fmaf(y1, y1, fmaf(y2, y2, y3 * y3)));
        #pragma unroll
        for (int m = 32; m >= 1; m >>= 1) {
            s1 += __shfl_xor(s1, m);
            s2 += __shfl_xor(s2, m);
        }
        const float mu  = s1 * (1.f / D);
        const float var = s2 * (1.f / D) - mu * mu;
        const float rs  = rsqrtf(var + LN_EPS);

        const float t0 = fmaxf((y0 - mu) * rs * g4.x + b4.x, 0.f);
        const float t1 = fmaxf((y1 - mu) * rs * g4.y + b4.y, 0.f);
        const float t2 = fmaxf((y2 - mu) * rs * g4.z + b4.z, 0.f);
        const float t3 = fmaxf((y3 - mu) * rs * g4.w + b4.w, 0.f);

        float ph[H];
        #pragma unroll
        for (int h = 0; h < H; ++h)
            ph[h] = fmaf(t0, w[h].x, fmaf(t1, w[h].y, fmaf(t2, w[h].z, t3 * w[h].w)));

        // value-splitting butterfly over 8 partials
        {
            const bool hi = (lane & 1);
            float k0 = hi ? ph[4] : ph[0], d0 = hi ? ph[0] : ph[4];
            float k1 = hi ? ph[5] : ph[1], d1 = hi ? ph[1] : ph[5];
            float k2 = hi ? ph[6] : ph[2], d2 = hi ? ph[2] : ph[6];
            float k3 = hi ? ph[7] : ph[3], d3 = hi ? ph[3] : ph[7];
            ph[0] = k0 + __shfl_xor(d0, 1);
            ph[1] = k1 + __shfl_xor(d1, 1);
            ph[2] = k2 + __shfl_xor(d2, 1);
            ph[3] = k3 + __shfl_xor(d3, 1);
        }
        {
            const bool hi = (lane & 2);
            float k0 = hi ? ph[2] : ph[0], d0 = hi ? ph[0] : ph[2];
            float k1 = hi ? ph[3] : ph[1], d1 = hi ? ph[1] : ph[3];
            ph[0] = k0 + __shfl_xor(d0, 2);
            ph[1] = k1 + __shfl_xor(d1, 2);
        }
        {
            const bool hi = (lane & 4);
            float k0 = hi ? ph[1] : ph[0], d0 = hi ? ph[0] : ph[1];
            ph[0] = k0 + __shfl_xor(d0, 4);
        }
        ph[0] += __shfl_xor(ph[0], 8);
        ph[0] += __shfl_xor(ph[0], 16);
        ph[0] += __shfl_xor(ph[0], 32);

        if (lane < 8) escl[hmap][j] = ph[0] + ecl;
    }
    __syncthreads();

    // ---- Phase B: softmax (wave = head) ----
    const int h = wid;
    const int bh = b*H + h;
    const float qdv = qdkd[(b*T + i)*16 + h];
    const float ba0 = ba[0];
    const int j1 = 1 + lane, j2 = 65 + lane;
    const bool v1 = !(i >= 1 && j1 == i);
    const bool v2 = !(i >= 1 && j2 == i);

    float l1 = NEG_INF, l2 = NEG_INF;
    if (v1) {
        l1 = qdv + qdkd[(b*T + j1)*16 + 8 + h] + escl[h][j1] + ba0;
        if (i >= 1) {
            float pr = prior[(bh*S + (i-1))*S + (j1-1)];
            pr = fminf(fmaxf(pr, 1e-6f), 1.f - 1e-6f);
            l1 += logf(pr) - logf(1.f - pr);
        }
    }
    if (v2) {
        l2 = qdv + qdkd[(b*T + j2)*16 + 8 + h] + escl[h][j2] + ba0;
        if (i >= 1) {
            float pr = prior[(bh*S + (i-1))*S + (j2-1)];
            pr = fminf(fmaxf(pr, 1e-6f), 1.f - 1e-6f);
            l2 += logf(pr) - logf(1.f - pr);
        }
    }

    float m = fmaxf(l1, l2);
    #pragma unroll
    for (int mm = 32; mm >= 1; mm >>= 1) m = fmaxf(m, __shfl_xor(m, mm));
    const float e1 = v1 ? expf(l1 - m) : 0.f;
    const float e2 = v2 ? expf(l2 - m) : 0.f;
    float s = e1 + e2;
    #pragma unroll
    for (int mm = 32; mm >= 1; mm >>= 1) s += __shfl_xor(s, mm);
    const float inv = 1.f / s;
    const float a1 = e1 * inv, a2 = e2 * inv;

    float* arow = out_attn + (size_t)(bh*T + i)*T;
    arow[j1] = a1;
    arow[j2] = a2;
    if (lane == 0) arow[0] = 0.f;
    pat[h][j1] = a1;
    pat[h][j2] = a2;
    __syncthreads();

    // ---- Phase C: ctx ----
    const int d = lane & 31, half = lane >> 5;
    float acc = 0.f;
    const float* vb = v + (size_t)(b*T)*D + h*HD + d;
    #pragma unroll 4
    for (int jj = 0; jj < 64; ++jj) {
        const int j = 1 + half*64 + jj;
        acc = fmaf(pat[h][j], vb[j*D], acc);
    }
    acc += __shfl_xor(acc, 32);
    if (lane < 32)
        out_basis[((b*T + i)*H + h)*HD + d] = acc;
}

extern "C" void kernel_launch(void* const* d_in, const int* in_sizes, int n_in,
                              void* d_out, int out_size, void* d_ws, size_t ws_size,
                              hipStream_t stream) {
    const float* desc  = (const float*)d_in[0];
    const float* nv    = (const float*)d_in[1];
    const float* prior = (const float*)d_in[2];
    const float* Wq  = (const float*)d_in[3];
    const float* bq  = (const float*)d_in[4];
    const float* Wk  = (const float*)d_in[5];
    const float* bk  = (const float*)d_in[6];
    const float* Wv  = (const float*)d_in[7];
    const float* bv  = (const float*)d_in[8];
    const float* wa  = (const float*)d_in[9];
    const float* ba  = (const float*)d_in[10];
    const float* We1 = (const float*)d_in[11];
    const float* be1 = (const float*)d_in[12];
    const float* lng = (const float*)d_in[13];
    const float* lnb = (const float*)d_in[14];
    const float* We2 = (const float*)d_in[15];
    const float* be2 = (const float*)d_in[16];

    float* ws = (float*)d_ws;
    float* U    = ws; ws += B*S*D;
    float* V    = ws; ws += B*S*D;
    float* v    = ws; ws += B*T*D;
    float* W2aT = ws; ws += H*D;
    float* ec   = ws; ws += H;
    float* qdkd = ws; ws += B*T*16;

    float* out_basis = (float*)d_out;
    float* out_attn  = out_basis + B*T*H*HD;

    gemm_all<<<dim3(259), 256, 0, stream>>>(nv, desc, Wq, bq, Wk, bk, Wv, bv,
                                            We1, be1, We2, be2, wa,
                                            v, U, V, qdkd, W2aT, ec);
    edge_attn<<<dim3(B*T), 512, 0, stream>>>(U, V, W2aT, ec, lng, lnb,
                                             qdkd, prior, v, ba,
                                             out_basis, out_attn);
}